// Round 4
// baseline (900.805 us; speedup 1.0000x reference)
//
#include <hip/hip_runtime.h>

// Attention w/ deterministic JAX threefry dropout (p=0.9), scale = *8 (ref divides by D^-0.5).
// B=4 H=16 S=2048 D=64 fp32. Flash-style, fp32 VALU QK^T (logits sigma~64 + x10 dropout
// rescale forbid bf16 logits). Dropout mask bit-exact vs jax.random.bernoulli(key(42), 0.1):
// PARTITIONABLE threefry (JAX >= 0.4.30 default):
//   counter = uint64 iota -> (hi=0, lo=idx); bits32 = x0 ^ x1 (xor-fold, prng.py bit_width=32).
// R2/R3 used x1 alone -> wrong mask -> absmax stuck at max|ref| = 52.25 (uncorrelated mask
// zeroes ref's peak with p=0.9). R3's launch beacon proved the kernel executes.
// LDS: Kt/Pt alias one buffer -> 51200 B (< 64 KiB WG limit; R1's 69632 B never launched).

#define S_LEN 2048
#define D_DIM 64
#define BM 64
#define BN 64
#define LD 68                 // padded leading dim (dwords), %4==0 keeps float4 LDS alignment
#define LDV 64                // V row-major: 4*tx pattern is 2-way bank aliasing (free, m136)
#define NTILES (S_LEN / BN)   // 32
#define E_THR 1e-7f
#define FLAG_MARGIN 16.2f

__device__ __forceinline__ unsigned int rotl32(unsigned int x, int n) {
  return (x << n) | (x >> (32 - n));
}

// JAX threefry2x32, key (0,42): ks0=0, ks1=42, ks2=42^0x1BD11BDA=0x1BD11BF0.
// Partitionable counter (hi,lo) = (0, idx); 20 rounds; 32-bit output = x0 ^ x1.
__device__ __forceinline__ unsigned int threefry_42_xorfold(unsigned int idx) {
  const unsigned int ks1 = 42u, ks2 = 0x1BD11BF0u;
  unsigned int x0 = 0u;             // c_hi (=0) + ks0 (=0)
  unsigned int x1 = idx + ks1;      // c_lo + ks1
#define TF4(a, b, c, d)                          \
  x0 += x1; x1 = rotl32(x1, a); x1 ^= x0;        \
  x0 += x1; x1 = rotl32(x1, b); x1 ^= x0;        \
  x0 += x1; x1 = rotl32(x1, c); x1 ^= x0;        \
  x0 += x1; x1 = rotl32(x1, d); x1 ^= x0;
  TF4(13, 15, 26, 6)
  x0 += ks1; x1 += ks2 + 1u;
  TF4(17, 29, 16, 24)
  x0 += ks2; x1 += 2u;              // + ks0 + 2
  TF4(13, 15, 26, 6)
  x1 += ks1 + 3u;                   // x0 += ks0 (=0)
  TF4(17, 29, 16, 24)
  x0 += ks1; x1 += ks2 + 4u;
  TF4(13, 15, 26, 6)
  x0 += ks2; x1 += 5u;              // final inject: x0 += ks2, x1 += ks0 + 5
#undef TF4
  return x0 ^ x1;                   // prng.py partitionable bit_width=32: bits1 ^ bits2
}

__global__ void attn_dropout_kernel(const float* __restrict__ q,
                                    const float* __restrict__ k,
                                    const float* __restrict__ v,
                                    float* __restrict__ out) {
  __shared__ float Qt[D_DIM * LD];      // Q transposed: Qt[d][i]           (17408 B)
  __shared__ float KtPt[D_DIM * LD];    // phase 1: K^T[d][j]; phase 2: P^T[j][i] (17408 B)
  __shared__ float Vs[BN * LDV];        // V row-major: Vs[j][d]            (16384 B)
  __shared__ unsigned int colmaskW[2];  // nonzero-column bitmask for PV skip

  const int t = threadIdx.x;
  const int tx = t & 15;                // -> 4 cols (QK) / 4 out-dims (PV)
  const int ty = t >> 4;                // -> 4 rows
  const int i0 = blockIdx.x * BM;
  const int bh = blockIdx.y;            // 0..63 (= b*16 + h)

  const float* Qg = q + ((size_t)bh * S_LEN + i0) * D_DIM;
  const float* Kg = k + (size_t)bh * S_LEN * D_DIM;
  const float* Vg = v + (size_t)bh * S_LEN * D_DIM;

  // ---- stage Q transposed (once) ----
  {
    const int d0 = tx * 4;
#pragma unroll
    for (int ii = 0; ii < 4; ++ii) {
      const int row = ty * 4 + ii;
      float4 q4 = *(const float4*)(Qg + row * D_DIM + d0);
      Qt[(d0 + 0) * LD + row] = q4.x;
      Qt[(d0 + 1) * LD + row] = q4.y;
      Qt[(d0 + 2) * LD + row] = q4.z;
      Qt[(d0 + 3) * LD + row] = q4.w;
    }
  }

  float o[4][4] = {};                   // o[row][dim]
  float lp[4] = {0.f, 0.f, 0.f, 0.f};   // per-lane partial softmax denominator
  float m[4] = {-1e30f, -1e30f, -1e30f, -1e30f};

  const unsigned int bh_base = (unsigned int)bh * (unsigned int)(S_LEN * S_LEN);

  for (int tile = 0; tile < NTILES; ++tile) {
    const int j0 = tile * BN;
    __syncthreads();  // (A) previous tile's PV reads of KtPt/Vs/colmask done

    // ---- stage K (transposed) + V (row-major); zero colmask ----
    if (t == 0) { colmaskW[0] = 0u; colmaskW[1] = 0u; }
    {
      const int d0 = tx * 4;
#pragma unroll
      for (int jj = 0; jj < 4; ++jj) {
        const int row = ty * 4 + jj;
        float4 k4 = *(const float4*)(Kg + (j0 + row) * D_DIM + d0);
        KtPt[(d0 + 0) * LD + row] = k4.x;
        KtPt[(d0 + 1) * LD + row] = k4.y;
        KtPt[(d0 + 2) * LD + row] = k4.z;
        KtPt[(d0 + 3) * LD + row] = k4.w;
        float4 v4 = *(const float4*)(Vg + (j0 + row) * D_DIM + d0);
        *(float4*)&Vs[row * LDV + d0] = v4;
      }
    }
    __syncthreads();  // (B) staging visible

    // ---- QK^T: acc[ii][jj] = sum_d Q[i][d]*K[j][d], fp32 ----
    float acc[4][4] = {};
    {
      const float* QtC = &Qt[ty * 4];
      const float* KtC = &KtPt[tx * 4];
#pragma unroll 8
      for (int d = 0; d < D_DIM; ++d) {
        float4 q4 = *(const float4*)(QtC + d * LD);
        float4 k4 = *(const float4*)(KtC + d * LD);
        float qa[4] = {q4.x, q4.y, q4.z, q4.w};
        float kb[4] = {k4.x, k4.y, k4.z, k4.w};
#pragma unroll
        for (int ii = 0; ii < 4; ++ii)
#pragma unroll
          for (int jj = 0; jj < 4; ++jj)
            acc[ii][jj] = fmaf(qa[ii], kb[jj], acc[ii][jj]);
      }
    }

    // ---- online softmax stats (logit = 8*acc, exact pow-2 scaling) ----
    float alpha[4];
    bool rflag[4];
#pragma unroll
    for (int ii = 0; ii < 4; ++ii) {
      float rmx = fmaxf(fmaxf(acc[ii][0], acc[ii][1]), fmaxf(acc[ii][2], acc[ii][3]));
#pragma unroll
      for (int off = 1; off < 16; off <<= 1)
        rmx = fmaxf(rmx, __shfl_xor(rmx, off, 16));
      const float lm = 8.f * rmx;
      const float mn = fmaxf(m[ii], lm);
      alpha[ii] = __expf(m[ii] - mn);
      rflag[ii] = (lm > mn - FLAG_MARGIN);  // tile contributes > ~1e-7 for this row?
      m[ii] = mn;
    }
#pragma unroll
    for (int ii = 0; ii < 4; ++ii) {
      lp[ii] *= alpha[ii];
#pragma unroll
      for (int dd = 0; dd < 4; ++dd) o[ii][dd] *= alpha[ii];
    }

    __syncthreads();  // (C) all QK reads of KtPt done before P^T overwrites it

    // ---- exp + exact threefry dropout; write P^T into KtPt; track nonzero cols ----
    unsigned int colbits = 0u;  // bit jj: column 4tx+jj has a nonzero P entry
#pragma unroll
    for (int jj = 0; jj < 4; ++jj) {
      float pst[4];
      bool nz = false;
#pragma unroll
      for (int ii = 0; ii < 4; ++ii) {
        float pv = 0.f;
        if (rflag[ii]) {
          const float e = __expf(fmaf(8.f, acc[ii][jj], -m[ii]));
          lp[ii] += e;  // denominator: ALL terms (dropout applies after softmax)
          if (e > E_THR) {
            const unsigned int idx = bh_base +
                (unsigned int)(i0 + ty * 4 + ii) * (unsigned int)S_LEN +
                (unsigned int)(j0 + tx * 4 + jj);
            const unsigned int r = threefry_42_xorfold(idx);
            const float u = __uint_as_float((r >> 9) | 0x3f800000u) - 1.0f;
            if (u < 0.1f) { pv = e; nz = true; }  // keep-prob = 0.1f, matches JAX
          }
        }
        pst[ii] = pv;
      }
      if (nz) colbits |= 1u << jj;
      *(float4*)&KtPt[(tx * 4 + jj) * LD + ty * 4] =
          make_float4(pst[0], pst[1], pst[2], pst[3]);
    }
    if (colbits) atomicOr(&colmaskW[tx >> 3], colbits << ((tx * 4) & 31));
    __syncthreads();  // (D) P^T + colmask visible

    // ---- PV over nonzero columns only (softmax near-one-hot + p=0.9 => P ~99.7% zero) ----
    const unsigned int cm0 = colmaskW[0], cm1 = colmaskW[1];  // block-uniform
#pragma unroll
    for (int w = 0; w < 2; ++w) {
      unsigned int mk = w ? cm1 : cm0;
      while (mk) {
        const int j = w * 32 + __builtin_ctz(mk);
        mk &= mk - 1;
        float4 p4 = *(const float4*)&KtPt[j * LD + ty * 4];   // broadcast across tx
        float4 v4 = *(const float4*)&Vs[j * LDV + tx * 4];
        float pa[4] = {p4.x, p4.y, p4.z, p4.w};
        float vb[4] = {v4.x, v4.y, v4.z, v4.w};
#pragma unroll
        for (int ii = 0; ii < 4; ++ii)
#pragma unroll
          for (int dd = 0; dd < 4; ++dd)
            o[ii][dd] = fmaf(pa[ii], vb[dd], o[ii][dd]);
      }
    }
  }

  // ---- epilogue: out = o * (10 / l); reduce l over the 16-lane row group ----
#pragma unroll
  for (int ii = 0; ii < 4; ++ii) {
    float lsum = lp[ii];
#pragma unroll
    for (int off = 1; off < 16; off <<= 1)
      lsum += __shfl_xor(lsum, off, 16);
    const float scale = 10.0f / lsum;  // ref: x / 0.1f; rel diff 1.5e-8, irrelevant
    *(float4*)(out + ((size_t)bh * S_LEN + (i0 + ty * 4 + ii)) * D_DIM + tx * 4) =
        make_float4(o[ii][0] * scale, o[ii][1] * scale,
                    o[ii][2] * scale, o[ii][3] * scale);
  }
}

extern "C" void kernel_launch(void* const* d_in, const int* in_sizes, int n_in,
                              void* d_out, int out_size, void* d_ws, size_t ws_size,
                              hipStream_t stream) {
  (void)in_sizes; (void)n_in; (void)d_ws; (void)ws_size;
  const float* q = (const float*)d_in[0];
  const float* k = (const float*)d_in[1];
  const float* v = (const float*)d_in[2];
  float* out = (float*)d_out;

  dim3 grid(S_LEN / BM, 64);  // 32 i-tiles x (B*H=64)
  attn_dropout_kernel<<<grid, 256, 0, stream>>>(q, k, v, out);

  // Launch-error beacon: paint d_out 0x42 (fp32 ~48.56 -> absmax err ~100.8) iff the
  // launch was rejected, so "launch failed" is distinguishable from "wrong mask" (52.25).
  if (hipGetLastError() != hipSuccess) {
    hipMemsetAsync(d_out, 0x42, (size_t)out_size * sizeof(float), stream);
  }
}

// Round 6
// 788.997 us; speedup vs baseline: 1.1417x; 1.1417x over previous
//
#include <hip/hip_runtime.h>

// Attention w/ deterministic JAX threefry dropout (p=0.9), scale = *8 (ref divides by D^-0.5).
// B=4 H=16 S=2048 D=64 fp32. Flash-style, fp32 VALU QK^T (no fp32 MFMA on CDNA4).
// Dropout mask bit-exact: threefry2x32 key(0,42), partitionable xor-fold (verified R4).
// R4: 900us, VALUBusy 55%, 6.6e7 bank conflicts. R5 rewrite: conflict-free j=tx+16*jj layout,
// P in registers (PV via __shfl + per-wave __ballot colmask), V direct from global —
// but K staging only covered dims 0..15 (1 float4/thread, needed 4) -> absmax 64.125.
// R6 = R5 + full K staging (4 chunks/thread, coalesced, 2-way LDS writes = free).

#define S_LEN 2048
#define D_DIM 64
#define BM 128                // Q rows per block (8 per thread)
#define BN 64                 // K rows per tile  (4 per thread, j = tx + 16*jj)
#define LDK 68                // padded K leading dim (dwords): QK read start-bank = 4*tx,
                              // 16 distinct addrs x 4-lane broadcast -> conflict-free
#define NTILES (S_LEN / BN)   // 32
#define E_THR 1e-7f
#define FLAG_MARGIN 16.2f

__device__ __forceinline__ unsigned int rotl32(unsigned int x, int n) {
  return (x << n) | (x >> (32 - n));
}

// JAX threefry2x32, key (0,42): ks=(0,42,0x1BD11BF0); counter (hi,lo)=(0,idx); 20 rounds;
// partitionable 32-bit output = x0 ^ x1 (verified bit-exact R4).
__device__ __forceinline__ unsigned int threefry_42_xorfold(unsigned int idx) {
  const unsigned int ks1 = 42u, ks2 = 0x1BD11BF0u;
  unsigned int x0 = 0u;
  unsigned int x1 = idx + ks1;
#define TF4(a, b, c, d)                          \
  x0 += x1; x1 = rotl32(x1, a); x1 ^= x0;        \
  x0 += x1; x1 = rotl32(x1, b); x1 ^= x0;        \
  x0 += x1; x1 = rotl32(x1, c); x1 ^= x0;        \
  x0 += x1; x1 = rotl32(x1, d); x1 ^= x0;
  TF4(13, 15, 26, 6)
  x0 += ks1; x1 += ks2 + 1u;
  TF4(17, 29, 16, 24)
  x0 += ks2; x1 += 2u;
  TF4(13, 15, 26, 6)
  x1 += ks1 + 3u;
  TF4(17, 29, 16, 24)
  x0 += ks1; x1 += ks2 + 4u;
  TF4(13, 15, 26, 6)
  x0 += ks2; x1 += 5u;
#undef TF4
  return x0 ^ x1;
}

__global__ __launch_bounds__(256, 3) void attn_dropout_kernel(
    const float* __restrict__ q, const float* __restrict__ k,
    const float* __restrict__ v, float* __restrict__ out) {
  __shared__ float Qs[BM * D_DIM];   // Q row-major, unpadded (reads are broadcasts)  32768 B
  __shared__ float Ks[BN * LDK];     // K row-major, padded                           17408 B

  const int t = threadIdx.x;
  const int tx = t & 15;             // j = tx + 16*jj ; out-dim group = 4*tx
  const int ty = t >> 4;             // i = ty*8 + ii
  const int i0 = blockIdx.x * BM;
  const int bh = blockIdx.y;         // 0..63

  const float* Qg = q + ((size_t)bh * S_LEN + i0) * D_DIM;
  const float* Kg = k + (size_t)bh * S_LEN * D_DIM;
  const float* Vg = v + (size_t)bh * S_LEN * D_DIM;

  // ---- stage Q row-major (once): flat contiguous copy, conflict-free b128 ----
#pragma unroll
  for (int r = 0; r < 8; ++r) {
    const int chunk = t + 256 * r;       // 0..2047 16B-chunks (128 rows x 16 chunks)
    *(float4*)&Qs[chunk * 4] = *(const float4*)(Qg + chunk * 4);
  }

  float o[8][4] = {};                    // o[ii][dd]
  float lp[8] = {};                      // per-lane partial denominators
  float m[8];
#pragma unroll
  for (int ii = 0; ii < 8; ++ii) m[ii] = -1e30f;

  const unsigned int bh_base = (unsigned int)bh * (unsigned int)(S_LEN * S_LEN);

  for (int tile = 0; tile < NTILES; ++tile) {
    const int j0 = tile * BN;
    __syncthreads();  // (A) previous tile's QK reads of Ks done

    // ---- stage K row-major: 64 rows x 16 chunks = 1024 float4s, 4 per thread ----
    // (R5 BUG was here: staged only 256 chunks -> dims 16..63 garbage.)
#pragma unroll
    for (int r = 0; r < 4; ++r) {
      const int c = t + 256 * r;         // 0..1023
      const int row = c >> 4, col = (c & 15) * 4;
      *(float4*)&Ks[row * LDK + col] = *(const float4*)(Kg + (j0 + row) * D_DIM + col);
    }
    __syncthreads();  // (B) staging visible

    // ---- QK^T: acc[ii][jj] = Q[ty*8+ii] . K[tx+16*jj], fp32 ----
    float acc[8][4] = {};
    {
      const float* Qb = &Qs[(ty * 8) * D_DIM];
      const float* Kb = &Ks[tx * LDK];
#pragma unroll 2
      for (int d0 = 0; d0 < D_DIM; d0 += 4) {
        float4 kf[4];
#pragma unroll
        for (int jj = 0; jj < 4; ++jj)
          kf[jj] = *(const float4*)(Kb + jj * 16 * LDK + d0);
#pragma unroll
        for (int ii = 0; ii < 8; ++ii) {
          float4 qf = *(const float4*)(Qb + ii * D_DIM + d0);
#pragma unroll
          for (int jj = 0; jj < 4; ++jj) {
            acc[ii][jj] = fmaf(qf.x, kf[jj].x, acc[ii][jj]);
            acc[ii][jj] = fmaf(qf.y, kf[jj].y, acc[ii][jj]);
            acc[ii][jj] = fmaf(qf.z, kf[jj].z, acc[ii][jj]);
            acc[ii][jj] = fmaf(qf.w, kf[jj].w, acc[ii][jj]);
          }
        }
      }
    }

    // ---- online softmax stats (logit = 8*acc, exact pow-2 scale) ----
    bool rflag[8];
#pragma unroll
    for (int ii = 0; ii < 8; ++ii) {
      float rmx = fmaxf(fmaxf(acc[ii][0], acc[ii][1]), fmaxf(acc[ii][2], acc[ii][3]));
#pragma unroll
      for (int off = 1; off < 16; off <<= 1)
        rmx = fmaxf(rmx, __shfl_xor(rmx, off, 16));
      const float lm = 8.f * rmx;
      const float mn = fmaxf(m[ii], lm);
      const float alpha = __expf(m[ii] - mn);
      rflag[ii] = (lm > mn - FLAG_MARGIN);   // tile contributes > ~1e-7 for this row?
      m[ii] = mn;
      lp[ii] *= alpha;
      o[ii][0] *= alpha; o[ii][1] *= alpha; o[ii][2] *= alpha; o[ii][3] *= alpha;
    }

    // ---- exp + exact threefry dropout, in-register; per-jj any-nonzero flags ----
    float pd[8][4];
    bool jjnz[4] = {false, false, false, false};
#pragma unroll
    for (int ii = 0; ii < 8; ++ii) {
#pragma unroll
      for (int jj = 0; jj < 4; ++jj) {
        float pv = 0.f;
        if (rflag[ii]) {
          const float e = __expf(fmaf(8.f, acc[ii][jj], -m[ii]));
          lp[ii] += e;  // denominator: ALL terms (dropout applies after softmax)
          if (e > E_THR) {
            const unsigned int idx = bh_base +
                (unsigned int)(i0 + ty * 8 + ii) * (unsigned int)S_LEN +
                (unsigned int)(j0 + tx + 16 * jj);
            const unsigned int r = threefry_42_xorfold(idx);
            const float u = __uint_as_float((r >> 9) | 0x3f800000u) - 1.0f;
            if (u < 0.1f) { pv = e; jjnz[jj] = true; }
          }
        }
        pd[ii][jj] = pv;
      }
    }

    // ---- per-WAVE nonzero-column mask (PV only needs this wave's own rows) ----
    unsigned long long colmask = 0ull;
#pragma unroll
    for (int jj = 0; jj < 4; ++jj) {
      unsigned long long b = __ballot(jjnz[jj]);
      unsigned long long m16 = (b | (b >> 16) | (b >> 32) | (b >> 48)) & 0xFFFFull;
      colmask |= m16 << (16 * jj);   // bit j = tx + 16*jj
    }

    // ---- PV over nonzero columns: P via __shfl (owner lane = j&15, slot = j>>4),
    //      V straight from global (L2/L3-resident; ~0.3 cols/wave/tile) ----
    while (colmask) {
      const int j = __builtin_ctzll(colmask);
      colmask &= colmask - 1;
      const int jw = j >> 4, jt = j & 15;      // wave-uniform
      const float4 v4 = *(const float4*)(Vg + (size_t)(j0 + j) * D_DIM + tx * 4);
#pragma unroll
      for (int ii = 0; ii < 8; ++ii) {
        float pj = (jw == 0) ? pd[ii][0] : (jw == 1) ? pd[ii][1]
                 : (jw == 2) ? pd[ii][2] : pd[ii][3];
        pj = __shfl(pj, jt, 16);               // broadcast within 16-lane row group
        o[ii][0] = fmaf(pj, v4.x, o[ii][0]);
        o[ii][1] = fmaf(pj, v4.y, o[ii][1]);
        o[ii][2] = fmaf(pj, v4.z, o[ii][2]);
        o[ii][3] = fmaf(pj, v4.w, o[ii][3]);
      }
    }
  }

  // ---- epilogue: out = o * (10 / l); reduce l over the 16-lane row group ----
#pragma unroll
  for (int ii = 0; ii < 8; ++ii) {
    float lsum = lp[ii];
#pragma unroll
    for (int off = 1; off < 16; off <<= 1)
      lsum += __shfl_xor(lsum, off, 16);
    const float scale = 10.0f / lsum;  // ref: x / 0.1f; rel diff 1.5e-8, irrelevant
    *(float4*)(out + ((size_t)bh * S_LEN + (i0 + ty * 8 + ii)) * D_DIM + tx * 4) =
        make_float4(o[ii][0] * scale, o[ii][1] * scale,
                    o[ii][2] * scale, o[ii][3] * scale);
  }
}

extern "C" void kernel_launch(void* const* d_in, const int* in_sizes, int n_in,
                              void* d_out, int out_size, void* d_ws, size_t ws_size,
                              hipStream_t stream) {
  (void)in_sizes; (void)n_in; (void)d_ws; (void)ws_size;
  const float* q = (const float*)d_in[0];
  const float* k = (const float*)d_in[1];
  const float* v = (const float*)d_in[2];
  float* out = (float*)d_out;

  dim3 grid(S_LEN / BM, 64);  // 16 i-tiles x (B*H=64)
  attn_dropout_kernel<<<grid, 256, 0, stream>>>(q, k, v, out);

  // Launch-failure beacon (absmax err ~100.8 instead of silent wrong output).
  if (hipGetLastError() != hipSuccess) {
    hipMemsetAsync(d_out, 0x42, (size_t)out_size * sizeof(float), stream);
  }
}

// Round 7
// 447.334 us; speedup vs baseline: 2.0137x; 1.7638x over previous
//
#include <hip/hip_runtime.h>

// Attention w/ deterministic JAX threefry dropout (p=0.9), scale = *8 (ref divides by D^-0.5).
// B=4 H=16 S=2048 D=64 fp32. R6 (fp32 VALU QK^T) = 763us, LDS-pipe-bound (~494us floor) +
// VGPR spill (WRITE 52MB vs 33.5MB out). R7: QK^T via bf16x3-split MFMA (16x16x32):
// q*k ~ qh*kh + qh*kl + ql*kh, dropped lo*lo <= 2^-18 rel -> logit err ~1e-4 (safe vs 1.045).
// P stays in C-frag registers (overwritten by dropout result), sparse PV via __ballot colmask
// + __shfl, V direct from global. Threefry2x32 key(0,42) partitionable xor-fold (verified R4).
// Layouts (guide, m89/m91/m120): A/B frag: lane row=l&15, k=(l>>4)*8+j (8 bf16 = b128);
// C/D: col=l&15, row=(l>>4)*4+reg. LDB=72 pads frag reads conflict-free. LDS 36864 B.

typedef short short8 __attribute__((ext_vector_type(8)));
typedef float floatx4 __attribute__((ext_vector_type(4)));

#define S_LEN 2048
#define D_DIM 64
#define BM 64                 // Q rows per block: wave w owns rows 16w..16w+15
#define BN 64                 // K rows per j-tile: 4 sub-tiles (jj) of 16
#define LDB 72                // bf16 leading dim: 144 B rows -> frag reads 16B-aligned, 2-way max
#define NTILES (S_LEN / BN)   // 32
#define E_THR 1e-7f
#define FLAG_MARGIN 16.2f

__device__ __forceinline__ unsigned int rotl32(unsigned int x, int n) {
  return (x << n) | (x >> (32 - n));
}

// JAX threefry2x32, key (0,42): ks=(0,42,0x1BD11BF0); counter (hi,lo)=(0,idx); 20 rounds;
// partitionable 32-bit output = x0 ^ x1 (verified bit-exact R4/R6).
__device__ __forceinline__ unsigned int threefry_42_xorfold(unsigned int idx) {
  const unsigned int ks1 = 42u, ks2 = 0x1BD11BF0u;
  unsigned int x0 = 0u;
  unsigned int x1 = idx + ks1;
#define TF4(a, b, c, d)                          \
  x0 += x1; x1 = rotl32(x1, a); x1 ^= x0;        \
  x0 += x1; x1 = rotl32(x1, b); x1 ^= x0;        \
  x0 += x1; x1 = rotl32(x1, c); x1 ^= x0;        \
  x0 += x1; x1 = rotl32(x1, d); x1 ^= x0;
  TF4(13, 15, 26, 6)
  x0 += ks1; x1 += ks2 + 1u;
  TF4(17, 29, 16, 24)
  x0 += ks2; x1 += 2u;
  TF4(13, 15, 26, 6)
  x1 += ks1 + 3u;
  TF4(17, 29, 16, 24)
  x0 += ks1; x1 += ks2 + 4u;
  TF4(13, 15, 26, 6)
  x0 += ks2; x1 += 5u;
#undef TF4
  return x0 ^ x1;
}

__device__ __forceinline__ unsigned int bf16rn(float x) {
  unsigned int u = __float_as_uint(x);
  return (u + 0x7FFFu + ((u >> 16) & 1u)) >> 16;   // round-to-nearest-even bf16
}

// float4 -> packed bf16 hi (uint2) + bf16 lo (uint2); x ~ hi + lo to ~17 mantissa bits
__device__ __forceinline__ void cvt4_split(float4 x, uint2* hp, uint2* lop) {
  const unsigned int h0 = bf16rn(x.x), h1 = bf16rn(x.y), h2 = bf16rn(x.z), h3 = bf16rn(x.w);
  const float f0 = __uint_as_float(h0 << 16), f1 = __uint_as_float(h1 << 16);
  const float f2 = __uint_as_float(h2 << 16), f3 = __uint_as_float(h3 << 16);
  const unsigned int l0 = bf16rn(x.x - f0), l1 = bf16rn(x.y - f1);
  const unsigned int l2 = bf16rn(x.z - f2), l3 = bf16rn(x.w - f3);
  hp->x = h0 | (h1 << 16); hp->y = h2 | (h3 << 16);
  lop->x = l0 | (l1 << 16); lop->y = l2 | (l3 << 16);
}

__global__ __launch_bounds__(256, 4) void attn_dropout_kernel(
    const float* __restrict__ q, const float* __restrict__ k,
    const float* __restrict__ v, float* __restrict__ out) {
  __shared__ unsigned short Qh[BM * LDB];   // 9216 B each
  __shared__ unsigned short Ql[BM * LDB];
  __shared__ unsigned short Kh[BN * LDB];
  __shared__ unsigned short Kl[BN * LDB];

  const int t = threadIdx.x;
  const int w = t >> 6;               // wave 0..3 -> rows 16w..16w+15
  const int m16 = t & 15;             // frag row select (A/B) and C col
  const int qd = (t & 63) >> 4;       // quad 0..3 -> C rows 4qd..4qd+3
  const int i0 = blockIdx.x * BM;
  const int bh = blockIdx.y;          // 0..63

  const float* Qg = q + ((size_t)bh * S_LEN + i0) * D_DIM;
  const float* Kg = k + (size_t)bh * S_LEN * D_DIM;
  const float* Vg = v + (size_t)bh * S_LEN * D_DIM;

  // ---- stage Q hi/lo (once): 64x64 fp32 -> bf16 split; 4 float4 per thread ----
#pragma unroll
  for (int rr = 0; rr < 4; ++rr) {
    const int e4 = t + 256 * rr;      // 0..1023 float4 chunks (16 per row)
    const int row = e4 >> 4, c4 = (e4 & 15) * 4;
    float4 x = *(const float4*)(Qg + row * D_DIM + c4);
    uint2 hp, lp2;
    cvt4_split(x, &hp, &lp2);
    *(uint2*)&Qh[row * LDB + c4] = hp;
    *(uint2*)&Ql[row * LDB + c4] = lp2;
  }

  float o[4][4] = {};                 // o[reg-row r][dim dd]; dims = 4*m16 + dd
  float lp[4] = {};                   // softmax denominators for quad rows
  float mrow[4];
#pragma unroll
  for (int r = 0; r < 4; ++r) mrow[r] = -1e30f;

  const unsigned int bh_base = (unsigned int)bh * (unsigned int)(S_LEN * S_LEN);

  for (int tile = 0; tile < NTILES; ++tile) {
    const int j0 = tile * BN;
    __syncthreads();  // (A) previous tile's frag reads done (also covers Q staging, tile 0)

    // ---- stage K hi/lo ----
#pragma unroll
    for (int rr = 0; rr < 4; ++rr) {
      const int e4 = t + 256 * rr;
      const int row = e4 >> 4, c4 = (e4 & 15) * 4;
      float4 x = *(const float4*)(Kg + (size_t)(j0 + row) * D_DIM + c4);
      uint2 hp, lp2;
      cvt4_split(x, &hp, &lp2);
      *(uint2*)&Kh[row * LDB + c4] = hp;
      *(uint2*)&Kl[row * LDB + c4] = lp2;
    }
    __syncthreads();  // (B) staging visible

    // ---- QK^T via bf16x3 MFMA: acc[jj] = 16x16 tile (rows 16w.., cols j0+16jj..) ----
    const int arow = 16 * w + m16;
    short8 ah0 = *(const short8*)&Qh[arow * LDB +      qd * 8];
    short8 ah1 = *(const short8*)&Qh[arow * LDB + 32 + qd * 8];
    short8 al0 = *(const short8*)&Ql[arow * LDB +      qd * 8];
    short8 al1 = *(const short8*)&Ql[arow * LDB + 32 + qd * 8];

    floatx4 acc[4];
#pragma unroll
    for (int jj = 0; jj < 4; ++jj) {
      const int brow = 16 * jj + m16;
      short8 bh0 = *(const short8*)&Kh[brow * LDB +      qd * 8];
      short8 bh1 = *(const short8*)&Kh[brow * LDB + 32 + qd * 8];
      short8 bl0 = *(const short8*)&Kl[brow * LDB +      qd * 8];
      short8 bl1 = *(const short8*)&Kl[brow * LDB + 32 + qd * 8];
      floatx4 a = {0.f, 0.f, 0.f, 0.f};
      a = __builtin_amdgcn_mfma_f32_16x16x32_bf16(ah0, bh0, a, 0, 0, 0);
      a = __builtin_amdgcn_mfma_f32_16x16x32_bf16(ah1, bh1, a, 0, 0, 0);
      a = __builtin_amdgcn_mfma_f32_16x16x32_bf16(ah0, bl0, a, 0, 0, 0);
      a = __builtin_amdgcn_mfma_f32_16x16x32_bf16(ah1, bl1, a, 0, 0, 0);
      a = __builtin_amdgcn_mfma_f32_16x16x32_bf16(al0, bh0, a, 0, 0, 0);
      a = __builtin_amdgcn_mfma_f32_16x16x32_bf16(al1, bh1, a, 0, 0, 0);
      acc[jj] = a;
    }

    // ---- online softmax stats per quad-row (logit = 8*acc, exact pow-2 scale) ----
    bool rflag[4];
#pragma unroll
    for (int r = 0; r < 4; ++r) {
      float rmx = fmaxf(fmaxf(acc[0][r], acc[1][r]), fmaxf(acc[2][r], acc[3][r]));
#pragma unroll
      for (int off = 1; off < 16; off <<= 1)
        rmx = fmaxf(rmx, __shfl_xor(rmx, off, 16));   // reduce over the quad's 16 lanes
      const float lm = 8.f * rmx;
      const float mn = fmaxf(mrow[r], lm);
      const float alpha = __expf(mrow[r] - mn);
      rflag[r] = (lm > mn - FLAG_MARGIN);
      mrow[r] = mn;
      lp[r] *= alpha;
      o[r][0] *= alpha; o[r][1] *= alpha; o[r][2] *= alpha; o[r][3] *= alpha;
    }

    // ---- exp + threefry dropout in-place: acc[jj][r] := kept ? e : 0 ----
    bool jjnz[4] = {false, false, false, false};
#pragma unroll
    for (int jj = 0; jj < 4; ++jj) {
#pragma unroll
      for (int r = 0; r < 4; ++r) {
        float p = 0.f;
        if (rflag[r]) {
          const float e = __expf(fmaf(8.f, acc[jj][r], -mrow[r]));
          lp[r] += e;  // denominator sums ALL terms (dropout applies after softmax)
          if (e > E_THR) {
            const unsigned int idx = bh_base +
                (unsigned int)(i0 + 16 * w + 4 * qd + r) * (unsigned int)S_LEN +
                (unsigned int)(j0 + 16 * jj + m16);
            const unsigned int rr = threefry_42_xorfold(idx);
            const float u = __uint_as_float((rr >> 9) | 0x3f800000u) - 1.0f;
            if (u < 0.1f) { p = e; }
          }
        }
        acc[jj][r] = p;
        if (p != 0.f) jjnz[jj] = true;
      }
    }

    // ---- per-wave nonzero-column mask; col j = 16*jj + (lane&15) ----
    unsigned long long colmask = 0ull;
#pragma unroll
    for (int jj = 0; jj < 4; ++jj) {
      unsigned long long b = __ballot(jjnz[jj]);
      unsigned long long f = (b | (b >> 16) | (b >> 32) | (b >> 48)) & 0xFFFFull;
      colmask |= f << (16 * jj);
    }

    // ---- sparse PV: P from C-frag regs via __shfl; V direct from global ----
    while (colmask) {
      const int j = __builtin_ctzll(colmask);   // wave-uniform
      colmask &= colmask - 1;
      const int jc = j & 15, jj = j >> 4;
      const int src = (t & 48) | jc;            // lane in my quad holding col jc
      floatx4 pa;
      if (jj == 0) pa = acc[0]; else if (jj == 1) pa = acc[1];
      else if (jj == 2) pa = acc[2]; else pa = acc[3];
      const float p0 = __shfl(pa[0], src);
      const float p1 = __shfl(pa[1], src);
      const float p2 = __shfl(pa[2], src);
      const float p3 = __shfl(pa[3], src);
      const float4 v4 = *(const float4*)(Vg + (size_t)(j0 + j) * D_DIM + m16 * 4);
      o[0][0] = fmaf(p0, v4.x, o[0][0]); o[0][1] = fmaf(p0, v4.y, o[0][1]);
      o[0][2] = fmaf(p0, v4.z, o[0][2]); o[0][3] = fmaf(p0, v4.w, o[0][3]);
      o[1][0] = fmaf(p1, v4.x, o[1][0]); o[1][1] = fmaf(p1, v4.y, o[1][1]);
      o[1][2] = fmaf(p1, v4.z, o[1][2]); o[1][3] = fmaf(p1, v4.w, o[1][3]);
      o[2][0] = fmaf(p2, v4.x, o[2][0]); o[2][1] = fmaf(p2, v4.y, o[2][1]);
      o[2][2] = fmaf(p2, v4.z, o[2][2]); o[2][3] = fmaf(p2, v4.w, o[2][3]);
      o[3][0] = fmaf(p3, v4.x, o[3][0]); o[3][1] = fmaf(p3, v4.y, o[3][1]);
      o[3][2] = fmaf(p3, v4.z, o[3][2]); o[3][3] = fmaf(p3, v4.w, o[3][3]);
    }
  }

  // ---- epilogue: out = o * (10 / l); l reduced over the quad's 16 lanes ----
#pragma unroll
  for (int r = 0; r < 4; ++r) {
    float lsum = lp[r];
#pragma unroll
    for (int off = 1; off < 16; off <<= 1)
      lsum += __shfl_xor(lsum, off, 16);
    const float scale = 10.0f / lsum;   // ref: x / 0.1f; rel diff 1.5e-8
    const int row = i0 + 16 * w + 4 * qd + r;
    *(float4*)(out + ((size_t)bh * S_LEN + row) * D_DIM + m16 * 4) =
        make_float4(o[r][0] * scale, o[r][1] * scale,
                    o[r][2] * scale, o[r][3] * scale);
  }
}

extern "C" void kernel_launch(void* const* d_in, const int* in_sizes, int n_in,
                              void* d_out, int out_size, void* d_ws, size_t ws_size,
                              hipStream_t stream) {
  (void)in_sizes; (void)n_in; (void)d_ws; (void)ws_size;
  const float* q = (const float*)d_in[0];
  const float* k = (const float*)d_in[1];
  const float* v = (const float*)d_in[2];
  float* out = (float*)d_out;

  dim3 grid(S_LEN / BM, 64);  // 32 i-tiles x (B*H=64)
  attn_dropout_kernel<<<grid, 256, 0, stream>>>(q, k, v, out);

  // Launch-failure beacon (absmax err ~100.8 instead of silent stale output).
  if (hipGetLastError() != hipSuccess) {
    hipMemsetAsync(d_out, 0x42, (size_t)out_size * sizeof(float), stream);
  }
}

// Round 8
// 418.426 us; speedup vs baseline: 2.1528x; 1.0691x over previous
//
#include <hip/hip_runtime.h>

// Attention w/ deterministic JAX threefry dropout (p=0.9), scale = *8 (ref divides by D^-0.5).
// B=4 H=16 S=2048 D=64 fp32. R7 (bf16x3-split MFMA QK^T, in-register P, sparse PV) = 382us,
// VALUBusy 77% — dominated by the per-tile bf16-RNE split of K (~55% of VALU, redone 32x
// per K tile across i-blocks). R8: pre-pass kernel splits K ONCE into bf16 hi/lo planes in
// d_ws (truncation split, residual <= 2^-16 rel); main kernel stages K as a pure uint4 copy.
// Q frags live in registers (split once per block). Fallback to in-kernel split if ws < 32MB.
// Threefry2x32 key(0,42) partitionable xor-fold (verified R4). MFMA 16x16x32 bf16 layouts
// verified R7. LDS = K planes only: 18432 B.

typedef short short8 __attribute__((ext_vector_type(8)));
typedef float floatx4 __attribute__((ext_vector_type(4)));

#define S_LEN 2048
#define D_DIM 64
#define BM 64                 // Q rows per block: wave w owns rows 16w..16w+15
#define BN 64                 // K rows per j-tile: 4 sub-tiles (jj) of 16
#define LDB 72                // bf16 leading dim: 144 B rows -> frag b128 reads 2-way max (free)
#define NTILES (S_LEN / BN)   // 32
#define E_THR 1e-7f
#define FLAG_MARGIN 16.2f
#define K_ELEMS (64 * S_LEN * D_DIM)          // 8388608 elements
#define WS_NEEDED ((size_t)K_ELEMS * 4)       // hi+lo bf16 planes = 33554432 B

__device__ __forceinline__ unsigned int rotl32(unsigned int x, int n) {
  return (x << n) | (x >> (32 - n));
}

// JAX threefry2x32, key (0,42): ks=(0,42,0x1BD11BF0); counter (hi,lo)=(0,idx); 20 rounds;
// partitionable 32-bit output = x0 ^ x1 (verified bit-exact R4/R6/R7).
__device__ __forceinline__ unsigned int threefry_42_xorfold(unsigned int idx) {
  const unsigned int ks1 = 42u, ks2 = 0x1BD11BF0u;
  unsigned int x0 = 0u;
  unsigned int x1 = idx + ks1;
#define TF4(a, b, c, d)                          \
  x0 += x1; x1 = rotl32(x1, a); x1 ^= x0;        \
  x0 += x1; x1 = rotl32(x1, b); x1 ^= x0;        \
  x0 += x1; x1 = rotl32(x1, c); x1 ^= x0;        \
  x0 += x1; x1 = rotl32(x1, d); x1 ^= x0;
  TF4(13, 15, 26, 6)
  x0 += ks1; x1 += ks2 + 1u;
  TF4(17, 29, 16, 24)
  x0 += ks2; x1 += 2u;
  TF4(13, 15, 26, 6)
  x1 += ks1 + 3u;
  TF4(17, 29, 16, 24)
  x0 += ks1; x1 += ks2 + 4u;
  TF4(13, 15, 26, 6)
  x0 += ks2; x1 += 5u;
#undef TF4
  return x0 ^ x1;
}

// Truncation split of 4 fp32 -> packed bf16 hi (uint2) + bf16 lo (uint2).
// hi = x chopped to bf16 (round-toward-zero); lo = (x - hi) chopped. |x-hi-lo| <= 2^-16|x|.
__device__ __forceinline__ void split4(float4 x, uint2* hp, uint2* lop) {
  const unsigned int u0 = __float_as_uint(x.x), u1 = __float_as_uint(x.y);
  const unsigned int u2 = __float_as_uint(x.z), u3 = __float_as_uint(x.w);
  hp->x = (u0 >> 16) | (u1 & 0xFFFF0000u);
  hp->y = (u2 >> 16) | (u3 & 0xFFFF0000u);
  const float l0 = x.x - __uint_as_float(u0 & 0xFFFF0000u);
  const float l1 = x.y - __uint_as_float(u1 & 0xFFFF0000u);
  const float l2 = x.z - __uint_as_float(u2 & 0xFFFF0000u);
  const float l3 = x.w - __uint_as_float(u3 & 0xFFFF0000u);
  lop->x = (__float_as_uint(l0) >> 16) | (__float_as_uint(l1) & 0xFFFF0000u);
  lop->y = (__float_as_uint(l2) >> 16) | (__float_as_uint(l3) & 0xFFFF0000u);
}

// 8 contiguous fp32 -> short8 hi + short8 lo (for Q register fragments)
__device__ __forceinline__ void split8(const float* x, short8* hi, short8* lo) {
  union { short8 s; uint2 u[2]; } h, l;
  split4(*(const float4*)(x + 0), &h.u[0], &l.u[0]);
  split4(*(const float4*)(x + 4), &h.u[1], &l.u[1]);
  *hi = h.s; *lo = l.s;
}

// ---- pre-pass: split K into bf16 hi/lo planes in workspace ----
__global__ void split_k_kernel(const float* __restrict__ k, unsigned short* __restrict__ khi,
                               unsigned short* __restrict__ klo) {
  const int c = blockIdx.x * 256 + threadIdx.x;   // one float4 chunk per thread
  if (c < K_ELEMS / 4) {
    float4 x = ((const float4*)k)[c];
    uint2 h, l;
    split4(x, &h, &l);
    ((uint2*)khi)[c] = h;
    ((uint2*)klo)[c] = l;
  }
}

__global__ __launch_bounds__(256, 4) void attn_dropout_kernel(
    const float* __restrict__ q, const float* __restrict__ k,
    const float* __restrict__ v, float* __restrict__ out,
    const unsigned short* __restrict__ khi, const unsigned short* __restrict__ klo,
    int usews) {
  __shared__ unsigned short Kh[BN * LDB];   // 9216 B each
  __shared__ unsigned short Kl[BN * LDB];

  const int t = threadIdx.x;
  const int w = t >> 6;               // wave 0..3 -> rows 16w..16w+15
  const int m16 = t & 15;             // frag row select (A/B) and C col
  const int qd = (t & 63) >> 4;       // quad 0..3 -> C rows 4qd..4qd+3
  const int i0 = blockIdx.x * BM;
  const int bh = blockIdx.y;          // 0..63

  const float* Qg = q + ((size_t)bh * S_LEN + i0) * D_DIM;
  const float* Kg = k + (size_t)bh * S_LEN * D_DIM;
  const float* Vg = v + (size_t)bh * S_LEN * D_DIM;
  const unsigned short* KhiG = khi + (size_t)bh * S_LEN * D_DIM;
  const unsigned short* KloG = klo + (size_t)bh * S_LEN * D_DIM;

  // ---- Q fragments -> registers, once (A layout: row=l&15, k=(l>>4)*8+j) ----
  short8 ah0, ah1, al0, al1;
  {
    const int arow = 16 * w + m16;
    float qbuf[8];
    *(float4*)&qbuf[0] = *(const float4*)(Qg + arow * D_DIM + qd * 8);
    *(float4*)&qbuf[4] = *(const float4*)(Qg + arow * D_DIM + qd * 8 + 4);
    split8(qbuf, &ah0, &al0);
    *(float4*)&qbuf[0] = *(const float4*)(Qg + arow * D_DIM + 32 + qd * 8);
    *(float4*)&qbuf[4] = *(const float4*)(Qg + arow * D_DIM + 32 + qd * 8 + 4);
    split8(qbuf, &ah1, &al1);
  }

  float o[4][4] = {};                 // o[reg-row r][dim dd]; dims = 4*m16 + dd
  float lp[4] = {};                   // softmax denominators for quad rows
  float mrow[4];
#pragma unroll
  for (int r = 0; r < 4; ++r) mrow[r] = -1e30f;

  const unsigned int bh_base = (unsigned int)bh * (unsigned int)(S_LEN * S_LEN);

  for (int tile = 0; tile < NTILES; ++tile) {
    const int j0 = tile * BN;
    __syncthreads();  // (A) previous tile's frag reads done

    if (usews) {
      // ---- stage K hi/lo planes: pure uint4 copy, zero conversion VALU ----
#pragma unroll
      for (int rr = 0; rr < 2; ++rr) {
        const int c = t + 256 * rr;          // 0..511 8-elem chunks
        const int row = c >> 3, c8 = (c & 7) * 8;
        *(uint4*)&Kh[row * LDB + c8] = *(const uint4*)&KhiG[(size_t)(j0 + row) * D_DIM + c8];
        *(uint4*)&Kl[row * LDB + c8] = *(const uint4*)&KloG[(size_t)(j0 + row) * D_DIM + c8];
      }
    } else {
      // ---- fallback: in-kernel truncation split from fp32 ----
#pragma unroll
      for (int rr = 0; rr < 4; ++rr) {
        const int c = t + 256 * rr;          // 0..1023 float4 chunks
        const int row = c >> 4, c4 = (c & 15) * 4;
        float4 x = *(const float4*)(Kg + (size_t)(j0 + row) * D_DIM + c4);
        uint2 h, l;
        split4(x, &h, &l);
        *(uint2*)&Kh[row * LDB + c4] = h;
        *(uint2*)&Kl[row * LDB + c4] = l;
      }
    }
    __syncthreads();  // (B) staging visible

    // ---- QK^T via bf16x3 MFMA (qh*kh + qh*kl + ql*kh; dropped lo*lo <= 2^-16 rel) ----
    floatx4 acc[4];
#pragma unroll
    for (int jj = 0; jj < 4; ++jj) {
      const int brow = 16 * jj + m16;
      short8 bh0 = *(const short8*)&Kh[brow * LDB +      qd * 8];
      short8 bh1 = *(const short8*)&Kh[brow * LDB + 32 + qd * 8];
      short8 bl0 = *(const short8*)&Kl[brow * LDB +      qd * 8];
      short8 bl1 = *(const short8*)&Kl[brow * LDB + 32 + qd * 8];
      floatx4 a = {0.f, 0.f, 0.f, 0.f};
      a = __builtin_amdgcn_mfma_f32_16x16x32_bf16(ah0, bh0, a, 0, 0, 0);
      a = __builtin_amdgcn_mfma_f32_16x16x32_bf16(ah1, bh1, a, 0, 0, 0);
      a = __builtin_amdgcn_mfma_f32_16x16x32_bf16(ah0, bl0, a, 0, 0, 0);
      a = __builtin_amdgcn_mfma_f32_16x16x32_bf16(ah1, bl1, a, 0, 0, 0);
      a = __builtin_amdgcn_mfma_f32_16x16x32_bf16(al0, bh0, a, 0, 0, 0);
      a = __builtin_amdgcn_mfma_f32_16x16x32_bf16(al1, bh1, a, 0, 0, 0);
      acc[jj] = a;
    }

    // ---- online softmax stats per quad-row (logit = 8*acc, exact pow-2 scale) ----
    bool rflag[4];
#pragma unroll
    for (int r = 0; r < 4; ++r) {
      float rmx = fmaxf(fmaxf(acc[0][r], acc[1][r]), fmaxf(acc[2][r], acc[3][r]));
#pragma unroll
      for (int off = 1; off < 16; off <<= 1)
        rmx = fmaxf(rmx, __shfl_xor(rmx, off, 16));   // reduce over the quad's 16 lanes
      const float lm = 8.f * rmx;
      const float mn = fmaxf(mrow[r], lm);
      const float alpha = __expf(mrow[r] - mn);
      rflag[r] = (lm > mn - FLAG_MARGIN);
      mrow[r] = mn;
      lp[r] *= alpha;
      o[r][0] *= alpha; o[r][1] *= alpha; o[r][2] *= alpha; o[r][3] *= alpha;
    }

    // ---- exp + threefry dropout in-place: acc[jj][r] := kept ? e : 0 ----
    bool jjnz[4] = {false, false, false, false};
#pragma unroll
    for (int jj = 0; jj < 4; ++jj) {
#pragma unroll
      for (int r = 0; r < 4; ++r) {
        float p = 0.f;
        if (rflag[r]) {
          const float e = __expf(fmaf(8.f, acc[jj][r], -mrow[r]));
          lp[r] += e;  // denominator sums ALL terms (dropout applies after softmax)
          if (e > E_THR) {
            const unsigned int idx = bh_base +
                (unsigned int)(i0 + 16 * w + 4 * qd + r) * (unsigned int)S_LEN +
                (unsigned int)(j0 + 16 * jj + m16);
            const unsigned int rr = threefry_42_xorfold(idx);
            const float u = __uint_as_float((rr >> 9) | 0x3f800000u) - 1.0f;
            if (u < 0.1f) { p = e; }
          }
        }
        acc[jj][r] = p;
        if (p != 0.f) jjnz[jj] = true;
      }
    }

    // ---- per-wave nonzero-column mask; col j = 16*jj + (lane&15) ----
    unsigned long long colmask = 0ull;
#pragma unroll
    for (int jj = 0; jj < 4; ++jj) {
      unsigned long long b = __ballot(jjnz[jj]);
      unsigned long long f = (b | (b >> 16) | (b >> 32) | (b >> 48)) & 0xFFFFull;
      colmask |= f << (16 * jj);
    }

    // ---- sparse PV: P from C-frag regs via __shfl; V direct from global ----
    while (colmask) {
      const int j = __builtin_ctzll(colmask);   // wave-uniform
      colmask &= colmask - 1;
      const int jc = j & 15, jj = j >> 4;
      const int src = (t & 48) | jc;            // lane in my quad holding col jc
      floatx4 pa;
      if (jj == 0) pa = acc[0]; else if (jj == 1) pa = acc[1];
      else if (jj == 2) pa = acc[2]; else pa = acc[3];
      const float p0 = __shfl(pa[0], src);
      const float p1 = __shfl(pa[1], src);
      const float p2 = __shfl(pa[2], src);
      const float p3 = __shfl(pa[3], src);
      const float4 v4 = *(const float4*)(Vg + (size_t)(j0 + j) * D_DIM + m16 * 4);
      o[0][0] = fmaf(p0, v4.x, o[0][0]); o[0][1] = fmaf(p0, v4.y, o[0][1]);
      o[0][2] = fmaf(p0, v4.z, o[0][2]); o[0][3] = fmaf(p0, v4.w, o[0][3]);
      o[1][0] = fmaf(p1, v4.x, o[1][0]); o[1][1] = fmaf(p1, v4.y, o[1][1]);
      o[1][2] = fmaf(p1, v4.z, o[1][2]); o[1][3] = fmaf(p1, v4.w, o[1][3]);
      o[2][0] = fmaf(p2, v4.x, o[2][0]); o[2][1] = fmaf(p2, v4.y, o[2][1]);
      o[2][2] = fmaf(p2, v4.z, o[2][2]); o[2][3] = fmaf(p2, v4.w, o[2][3]);
      o[3][0] = fmaf(p3, v4.x, o[3][0]); o[3][1] = fmaf(p3, v4.y, o[3][1]);
      o[3][2] = fmaf(p3, v4.z, o[3][2]); o[3][3] = fmaf(p3, v4.w, o[3][3]);
    }
  }

  // ---- epilogue: out = o * (10 / l); l reduced over the quad's 16 lanes ----
#pragma unroll
  for (int r = 0; r < 4; ++r) {
    float lsum = lp[r];
#pragma unroll
    for (int off = 1; off < 16; off <<= 1)
      lsum += __shfl_xor(lsum, off, 16);
    const float scale = 10.0f / lsum;   // ref: x / 0.1f; rel diff 1.5e-8
    const int row = i0 + 16 * w + 4 * qd + r;
    *(float4*)(out + ((size_t)bh * S_LEN + row) * D_DIM + m16 * 4) =
        make_float4(o[r][0] * scale, o[r][1] * scale,
                    o[r][2] * scale, o[r][3] * scale);
  }
}

extern "C" void kernel_launch(void* const* d_in, const int* in_sizes, int n_in,
                              void* d_out, int out_size, void* d_ws, size_t ws_size,
                              hipStream_t stream) {
  (void)in_sizes; (void)n_in;
  const float* q = (const float*)d_in[0];
  const float* k = (const float*)d_in[1];
  const float* v = (const float*)d_in[2];
  float* out = (float*)d_out;

  unsigned short* khi = (unsigned short*)d_ws;
  unsigned short* klo = khi + K_ELEMS;
  const int usews = (ws_size >= WS_NEEDED) ? 1 : 0;

  if (usews) {
    split_k_kernel<<<K_ELEMS / 4 / 256, 256, 0, stream>>>(k, khi, klo);
  }
  dim3 grid(S_LEN / BM, 64);  // 32 i-tiles x (B*H=64)
  attn_dropout_kernel<<<grid, 256, 0, stream>>>(q, k, v, out, khi, klo, usews);

  // Launch-failure beacon (absmax err ~100.8 instead of silent stale output).
  if (hipGetLastError() != hipSuccess) {
    hipMemsetAsync(d_out, 0x42, (size_t)out_size * sizeof(float), stream);
  }
}